// Round 3
// baseline (674.442 us; speedup 1.0000x reference)
//
#include <hip/hip_runtime.h>
#include <math.h>

// Problem constants
#define B_    128
#define R_    1152
#define C_    10
#define O_    16
#define I_    338
#define CO_   160          // C_*O_
#define SLAB  20480        // B_*CO_  (one r-slab of u_hat, contiguous)
#define RS_CHUNKS 16
#define R_PER_CHUNK 72     // 1152/16

// ---- uhat MFMA tiling ----
#define KT32   32          // fp32 K-elements per tile (one 16x16x32 MFMA K-span)
#define NKT32  11          // ceil(338/32)
#define TAIL   18          // 338 - 10*32 valid elements in last tile
#define LROWU  32          // LDS row stride in ushorts (64B rows, NO pad; swizzled)
// LDS row regions within one buffer (864 rows total, 55296 B / buffer):
#define RXH    0
#define RXM    128
#define RXL    256
#define RWH    384
#define RWM    544
#define RWL    704
#define BUFU   (864 * LROWU)   // ushorts per buffer

typedef __attribute__((ext_vector_type(8))) short bf16x8;  // 8 bf16 = 4 VGPR (MFMA A/B frag)
typedef __attribute__((ext_vector_type(4))) float f32x4;   // MFMA C/D frag

__device__ __forceinline__ unsigned short bf16_rne(float f) {
    unsigned int u = __float_as_uint(f);
    return (unsigned short)((u + 0x7fffu + ((u >> 16) & 1u)) >> 16);
}
// 3-term split, all RNE: f = h + m + l + eps, |eps| <= 2^-27 |f|.
// With the 6 leading cross-products kept, dropped terms <= 2^-26|x*w| --
// below fp32 fma noise, so u_hat is numerically equivalent to the fp32 GEMM.
__device__ __forceinline__ void cvt_split3(float f, unsigned short* h,
                                           unsigned short* m, unsigned short* l) {
    unsigned short hb = bf16_rne(f);
    float fh = __uint_as_float(((unsigned int)hb) << 16);
    float r1 = f - fh;
    unsigned short mb = bf16_rne(r1);
    float fm = __uint_as_float(((unsigned int)mb) << 16);
    float r2 = r1 - fm;
    unsigned short lb = bf16_rne(r2);
    *h = hb; *m = mb; *l = lb;
}

// ---------------------------------------------------------------------------
// u_hat[b,r,c,o] = sum_i W[r,c,o,i] * x[b,r,i]
// One block per r: M=128(b) x N=160(c*16+o) x K=338 GEMM via 3-term split-bf16
// MFMA:  x*w ~= xh*wh + xh*wm + xm*wh + xh*wl + xm*wm + xl*wh
//
// Round-3 structure: double-buffered LDS (110.6 KB, 1 block/CU) + T14 pipeline:
//   per tile: issue loads(t+1) -> ds_read+MFMA(t) -> vmcnt/cvt/ds_write(t+1)
//   -> ONE barrier.  Global-load latency hides under the MFMA burst.
// LDS bank swizzle: physical 16B chunk p = (c + row + (row>>2)) & 3 within each
// 64B row. Analytically conflict-free for both the b128 reads (8-lane groups
// span 8 aligned rows -> 32 distinct banks) and the 8B staging writes
// (16-lane groups span 2 rows -> the two 16-bank halves).  Collapses to a
// per-lane constant on the read side: (hi + lr + (lr>>2)) & 3.
// ---------------------------------------------------------------------------
__global__ __launch_bounds__(256) void uhat_kernel(const float* __restrict__ x,
                                                   const float* __restrict__ W,
                                                   float* __restrict__ u) {
    __shared__ __align__(16) unsigned short lds[2][BUFU];   // 110,592 B

    const int r    = blockIdx.x;
    const int tid  = threadIdx.x;
    const int lane = tid & 63;
    const int w    = tid >> 6;          // wave 0..3
    const int lr   = lane & 15;         // M-row (A) / N-col (B) / D-col
    const int hi   = lane >> 4;         // k-chunk (8 bf16 = 16B) index
    const int cSw  = (hi + lr + (lr >> 2)) & 3;   // read-side swizzled chunk

    // staging coords: q = tid + it*256; row = q>>3, kq = q&7 (4-elem group)
    const int r0s = tid >> 3;           // row base (it adds 32)
    const int kqx = tid & 7;
    const int cWw = ((kqx >> 1) + r0s + (r0s >> 2)) & 3;  // write-side chunk (const over it)
    const int eo  = (kqx & 1) * 4;                         // element offset in chunk

    const float* xr = x + (size_t)r * I_;
    const float* wr = W + (size_t)r * (CO_ * I_);

    float4 fx[4], fw[5];                // staged global data (tile t+1)

    auto issue_loads = [&](int kt) {
        const int k0 = kt * KT32;
        if (kt != NKT32 - 1) {
#pragma unroll
            for (int it = 0; it < 4; ++it) {
                int b = r0s + it * 32;
                fx[it] = *(const float4*)(xr + (size_t)b * (R_ * I_) + k0 + kqx * 4);
            }
#pragma unroll
            for (int it = 0; it < 5; ++it) {
                int co = r0s + it * 32;
                fw[it] = *(const float4*)(wr + (size_t)co * I_ + k0 + kqx * 4);
            }
        } else {
            const int kb = kqx * 4;
#pragma unroll
            for (int it = 0; it < 4; ++it) {
                int b = r0s + it * 32;
                const float* s = xr + (size_t)b * (R_ * I_) + k0 + kb;
                float4 f;
                f.x = (kb + 0 < TAIL) ? s[0] : 0.f;
                f.y = (kb + 1 < TAIL) ? s[1] : 0.f;
                f.z = (kb + 2 < TAIL) ? s[2] : 0.f;
                f.w = (kb + 3 < TAIL) ? s[3] : 0.f;
                fx[it] = f;
            }
#pragma unroll
            for (int it = 0; it < 5; ++it) {
                int co = r0s + it * 32;
                const float* s = wr + (size_t)co * I_ + k0 + kb;
                float4 f;
                f.x = (kb + 0 < TAIL) ? s[0] : 0.f;
                f.y = (kb + 1 < TAIL) ? s[1] : 0.f;
                f.z = (kb + 2 < TAIL) ? s[2] : 0.f;
                f.w = (kb + 3 < TAIL) ? s[3] : 0.f;
                fw[it] = f;
            }
        }
    };

    auto cvt_store = [&](int buf) {
        unsigned short* L = &lds[buf][0];
#pragma unroll
        for (int it = 0; it < 4; ++it) {
            int row = r0s + it * 32;
            float4 f = fx[it];
            ushort4 hv, mv, lv;
            cvt_split3(f.x, &hv.x, &mv.x, &lv.x);
            cvt_split3(f.y, &hv.y, &mv.y, &lv.y);
            cvt_split3(f.z, &hv.z, &mv.z, &lv.z);
            cvt_split3(f.w, &hv.w, &mv.w, &lv.w);
            int off = (RXH + row) * LROWU + cWw * 8 + eo;
            *(ushort4*)&L[off]                         = hv;
            *(ushort4*)&L[off + (RXM - RXH) * LROWU]   = mv;
            *(ushort4*)&L[off + (RXL - RXH) * LROWU]   = lv;
        }
#pragma unroll
        for (int it = 0; it < 5; ++it) {
            int row = r0s + it * 32;
            float4 f = fw[it];
            ushort4 hv, mv, lv;
            cvt_split3(f.x, &hv.x, &mv.x, &lv.x);
            cvt_split3(f.y, &hv.y, &mv.y, &lv.y);
            cvt_split3(f.z, &hv.z, &mv.z, &lv.z);
            cvt_split3(f.w, &hv.w, &mv.w, &lv.w);
            int off = (RWH + row) * LROWU + cWw * 8 + eo;
            *(ushort4*)&L[off]                         = hv;
            *(ushort4*)&L[off + (RWM - RWH) * LROWU]   = mv;
            *(ushort4*)&L[off + (RWL - RWH) * LROWU]   = lv;
        }
    };

    f32x4 acc[2][10];
#pragma unroll
    for (int mt = 0; mt < 2; ++mt)
#pragma unroll
        for (int n = 0; n < 10; ++n) acc[mt][n] = (f32x4){0.f, 0.f, 0.f, 0.f};

    auto compute = [&](int buf) {
        const unsigned short* L = &lds[buf][0];
        bf16x8 ah[2], am[2], al[2];
#pragma unroll
        for (int mt = 0; mt < 2; ++mt) {
            int row = w * 32 + mt * 16 + lr;
            int off = (RXH + row) * LROWU + cSw * 8;
            ah[mt] = *(const bf16x8*)&L[off];
            am[mt] = *(const bf16x8*)&L[off + (RXM - RXH) * LROWU];
            al[mt] = *(const bf16x8*)&L[off + (RXL - RXH) * LROWU];
        }
#pragma unroll
        for (int n = 0; n < 10; ++n) {
            int co = n * 16 + lr;
            int off = (RWH + co) * LROWU + cSw * 8;
            bf16x8 bh = *(const bf16x8*)&L[off];
            bf16x8 bm = *(const bf16x8*)&L[off + (RWM - RWH) * LROWU];
            bf16x8 bl = *(const bf16x8*)&L[off + (RWL - RWH) * LROWU];
#pragma unroll
            for (int mt = 0; mt < 2; ++mt) {
                acc[mt][n] = __builtin_amdgcn_mfma_f32_16x16x32_bf16(ah[mt], bh, acc[mt][n], 0, 0, 0);
                acc[mt][n] = __builtin_amdgcn_mfma_f32_16x16x32_bf16(ah[mt], bm, acc[mt][n], 0, 0, 0);
                acc[mt][n] = __builtin_amdgcn_mfma_f32_16x16x32_bf16(am[mt], bh, acc[mt][n], 0, 0, 0);
                acc[mt][n] = __builtin_amdgcn_mfma_f32_16x16x32_bf16(ah[mt], bl, acc[mt][n], 0, 0, 0);
                acc[mt][n] = __builtin_amdgcn_mfma_f32_16x16x32_bf16(am[mt], bm, acc[mt][n], 0, 0, 0);
                acc[mt][n] = __builtin_amdgcn_mfma_f32_16x16x32_bf16(al[mt], bh, acc[mt][n], 0, 0, 0);
            }
        }
    };

    // -------- pipeline --------
    issue_loads(0);
    cvt_store(0);
    __syncthreads();
    for (int t = 0; t < NKT32; ++t) {
        if (t + 1 < NKT32) issue_loads(t + 1);   // VMEM in flight across MFMA burst
        compute(t & 1);
        if (t + 1 < NKT32) cvt_store((t + 1) & 1);
        __syncthreads();
    }

    // ---- epilogue: D[row][col]: col = lane&15, row = (lane>>4)*4 + reg ----
    float* ur = u + (size_t)r * SLAB;
    const int rquad = hi * 4;
#pragma unroll
    for (int mt = 0; mt < 2; ++mt)
#pragma unroll
        for (int n = 0; n < 10; ++n)
#pragma unroll
            for (int reg = 0; reg < 4; ++reg) {
                int b = w * 32 + mt * 16 + rquad + reg;
                ur[b * CO_ + n * 16 + lr] = acc[mt][n][reg];
            }
}

// ---------------------------------------------------------------------------
// softmax over routes (axis r) per capsule c:  c_ij[r,c] = softmax_r(b_ij[r,c])
// ---------------------------------------------------------------------------
__global__ void softmax_kernel(const float* __restrict__ bij, float* __restrict__ cij) {
    const int c   = blockIdx.x;
    const int tid = threadIdx.x;
    __shared__ float redm[4];
    __shared__ float reds[4];
    __shared__ float bcast[2];

    float m = -1e30f;
    for (int r = tid; r < R_; r += 256) m = fmaxf(m, bij[r * C_ + c]);
#pragma unroll
    for (int off = 32; off > 0; off >>= 1) m = fmaxf(m, __shfl_down(m, off));
    if ((tid & 63) == 0) redm[tid >> 6] = m;
    __syncthreads();
    if (tid == 0) bcast[0] = fmaxf(fmaxf(redm[0], redm[1]), fmaxf(redm[2], redm[3]));
    __syncthreads();
    m = bcast[0];

    float s = 0.f;
    for (int r = tid; r < R_; r += 256) s += expf(bij[r * C_ + c] - m);
#pragma unroll
    for (int off = 32; off > 0; off >>= 1) s += __shfl_down(s, off);
    if ((tid & 63) == 0) reds[tid >> 6] = s;
    __syncthreads();
    if (tid == 0) bcast[1] = reds[0] + reds[1] + reds[2] + reds[3];
    __syncthreads();
    const float inv = 1.0f / bcast[1];
    for (int r = tid; r < R_; r += 256) cij[r * C_ + c] = expf(bij[r * C_ + c] - m) * inv;
}

// ---------------------------------------------------------------------------
// partial s over an r-chunk: partial[chunk, idx] = sum_{r in chunk} c_ij[r,c]*u[r,idx]
// float4 per thread (G13): 4 consecutive o of the same capsule c.
// grid: (SLAB/1024, RS_CHUNKS) x 256 threads
// ---------------------------------------------------------------------------
__global__ void v_partial_kernel(const float* __restrict__ u, const float* __restrict__ cij,
                                 float* __restrict__ partial) {
    const int q     = blockIdx.x * 256 + threadIdx.x;   // float4 id, 0..5119
    const int idx   = q << 2;
    const int chunk = blockIdx.y;
    const int c     = (idx >> 4) % 10;
    const int r0    = chunk * R_PER_CHUNK;
    const float4* up = (const float4*)(u + (size_t)r0 * SLAB + idx);
    const float* cp  = cij + r0 * C_ + c;
    float4 s = {0.f, 0.f, 0.f, 0.f};
#pragma unroll 8
    for (int rr = 0; rr < R_PER_CHUNK; ++rr) {
        float  cv = cp[rr * C_];
        float4 uu = up[(size_t)rr * (SLAB / 4)];
        s.x = fmaf(cv, uu.x, s.x);
        s.y = fmaf(cv, uu.y, s.y);
        s.z = fmaf(cv, uu.z, s.z);
        s.w = fmaf(cv, uu.w, s.w);
    }
    *(float4*)(partial + (size_t)chunk * SLAB + idx) = s;
}

// sum partials -> s -> squash -> v  (v = s*|s|/(1+s^2), identical to ref formula)
__global__ void v_finalize_kernel(const float* __restrict__ partial, float* __restrict__ v) {
    const int q   = blockIdx.x * 256 + threadIdx.x;     // float4 id
    const int idx = q << 2;
    float4 s = {0.f, 0.f, 0.f, 0.f};
#pragma unroll
    for (int ch = 0; ch < RS_CHUNKS; ++ch) {
        float4 p = *(const float4*)(partial + (size_t)ch * SLAB + idx);
        s.x += p.x; s.y += p.y; s.z += p.z; s.w += p.w;
    }
    float4 o;
    o.x = s.x * fabsf(s.x) / (1.0f + s.x * s.x);
    o.y = s.y * fabsf(s.y) / (1.0f + s.y * s.y);
    o.z = s.z * fabsf(s.z) / (1.0f + s.z * s.z);
    o.w = s.w * fabsf(s.w) / (1.0f + s.w * s.w);
    *(float4*)(v + idx) = o;
}

// ---------------------------------------------------------------------------
// agreement: b_ij[r,c] += (1/B) * sum_{b,o} u[r,b,c,o] * v[b,c,o]
// float4 loads over o-quads.
// ---------------------------------------------------------------------------
__global__ void agree_kernel(const float* __restrict__ u, const float* __restrict__ v,
                             float* __restrict__ bij) {
    const int r = blockIdx.x;
    const int l = threadIdx.x;   // 0..63
    const int c = threadIdx.y;   // 0..9
    const float* ur = u + (size_t)r * SLAB;
    float acc = 0.f;
#pragma unroll 4
    for (int k = l; k < B_ * 4; k += 64) {      // 512 o-quads
        int b = k >> 2, oq = k & 3;
        int off = b * CO_ + c * O_ + oq * 4;
        float4 uu = *(const float4*)&ur[off];
        float4 vv = *(const float4*)&v[off];
        acc = fmaf(uu.x, vv.x, acc);
        acc = fmaf(uu.y, vv.y, acc);
        acc = fmaf(uu.z, vv.z, acc);
        acc = fmaf(uu.w, vv.w, acc);
    }
#pragma unroll
    for (int off = 32; off > 0; off >>= 1) acc += __shfl_down(acc, off);
    if (l == 0) bij[r * C_ + c] += acc * (1.0f / B_);
}

// ---------------------------------------------------------------------------
extern "C" void kernel_launch(void* const* d_in, const int* in_sizes, int n_in,
                              void* d_out, int out_size, void* d_ws, size_t ws_size,
                              hipStream_t stream) {
    const float* x = (const float*)d_in[0];   // (B,R,I)
    const float* W = (const float*)d_in[1];   // (R,C,O,I)
    float* out = (float*)d_out;               // (B,C,O,1) = 20480 floats

    // workspace carve-up (floats): ~96 MB total
    float* ws      = (float*)d_ws;
    float* u       = ws;                                 // R_*SLAB = 23,592,960
    float* bij     = u + (size_t)R_ * SLAB;              // 11,520
    float* cij     = bij + R_ * C_;                      // 11,520
    float* partial = cij + R_ * C_;                      // 16*20480
    float* v       = partial + RS_CHUNKS * SLAB;         // 20,480

    hipMemsetAsync(bij, 0, R_ * C_ * sizeof(float), stream);
    uhat_kernel<<<R_, 256, 0, stream>>>(x, W, u);

    for (int it = 0; it < 3; ++it) {
        softmax_kernel<<<C_, 256, 0, stream>>>(bij, cij);
        dim3 g(SLAB / 1024, RS_CHUNKS);
        v_partial_kernel<<<g, 256, 0, stream>>>(u, cij, partial);
        float* vout = (it == 2) ? out : v;
        v_finalize_kernel<<<SLAB / 1024, 256, 0, stream>>>(partial, vout);
        if (it < 2) agree_kernel<<<R_, dim3(64, 10), 0, stream>>>(u, v, bij);
    }
}